// Round 6
// baseline (138.176 us; speedup 1.0000x reference)
//
#include <hip/hip_runtime.h>
#include <math.h>

// QGRUCell — Round 6: gather-style coalesced cvt (wave-per-chunk, 1KB
// contiguous writes) + main kernel at KT=16 with 32KB dbuf LDS for
// 3 blocks/CU (cross-block overlap hides the per-step vmcnt drain).

typedef _Float16 f16x8  __attribute__((ext_vector_type(8)));
typedef __bf16   bf16x8 __attribute__((ext_vector_type(8)));
typedef float    f32x16 __attribute__((ext_vector_type(16)));

namespace {

constexpr int Bsz = 8192, Ksz = 512, Hsz = 512;
constexpr int BM = 64, BN = 64;

// ws (f16 units): chunks of 512 f16 = 32 rows x 16 k, frag order
// pos(row,k) = (k>>3)*256 + row*8 + (k&7).
// A region: chunk(arr, M32, K16) = arr*8192 + M32*32 + K16, K16 in [0,32)
// W region: 16384 + (g*16 + N32)*32 + K16
constexpr unsigned WCH0    = 16384u;
constexpr unsigned NCHUNK  = 16384u + 3072u;          // 19456
constexpr unsigned WS_F16  = NCHUNK * 512u;           // 9,961,472 f16
constexpr size_t   WS_NEED = (size_t)WS_F16 * 2;      // 19,922,944 B

__device__ __forceinline__ float qround(float x, float s, float invs) {
    return floorf(x * s + 0.5f) * invs;
}

__device__ __forceinline__ float qsigmoid_dev(float x) {
    float iq = floorf(x * 134217728.0f + 0.5f);
    iq = fminf(fmaxf(iq, -2147483648.0f), 2147483648.0f);
    float e = __expf(-iq * 7.450580596923828125e-9f);
    float s = __builtin_amdgcn_rcpf(1.0f + e);
    float q31 = floorf(s * 2147483648.0f + 0.5f);
    float q15 = floorf(q31 * 1.52587890625e-5f + 0.5f);
    return q15 * 3.0517578125e-5f;
}

__device__ __forceinline__ float qtanh_dev(float x) {
    float iq = floorf(x * 134217728.0f + 0.5f);
    iq = fminf(fmaxf(iq, -2147483648.0f), 2147483648.0f);
    float z = iq * 7.450580596923828125e-9f;
    float e = __expf(2.0f * z);
    float t = 1.0f - 2.0f * __builtin_amdgcn_rcpf(e + 1.0f);
    float q31 = floorf(t * 2147483648.0f + 0.5f);
    float q15 = floorf(q31 * 1.52587890625e-5f + 0.5f);
    return q15 * 3.0517578125e-5f;
}

__device__ __forceinline__ void dma16(const void* g, void* l) {
    __builtin_amdgcn_global_load_lds(
        (const __attribute__((address_space(1))) unsigned int*)g,
        (__attribute__((address_space(3))) unsigned int*)l, 16, 0, 0);
}

__device__ __forceinline__ void split2(float a, float b, unsigned& hi, unsigned& lo) {
    unsigned ua = __float_as_uint(a); ua += 0x7fffu + ((ua >> 16) & 1u);
    unsigned ub = __float_as_uint(b); ub += 0x7fffu + ((ub >> 16) & 1u);
    hi = (ua >> 16) | (ub & 0xffff0000u);
    float ra = a - __uint_as_float(ua & 0xffff0000u);
    float rb = b - __uint_as_float(ub & 0xffff0000u);
    unsigned va = __float_as_uint(ra); va += 0x7fffu + ((va >> 16) & 1u);
    unsigned vb = __float_as_uint(rb); vb += 0x7fffu + ((vb >> 16) & 1u);
    lo = (va >> 16) | (vb & 0xffff0000u);
}

} // namespace

// ---------------- pre-pass: gather-transpose fp32 -> f16 chunks ------------
// One wave per chunk; lane l reads 8 consecutive f32 from source row (l&31),
// k-octet (l>>5); writes f16x8 at ws[c*512 + l*8] -> 1KB contiguous per wave.
__global__ __launch_bounds__(256) void cvt_gather_f16(
    const float* __restrict__ x, const float* __restrict__ h,
    const float* __restrict__ wih, const float* __restrict__ whh,
    _Float16* __restrict__ ws)
{
    const int wid  = threadIdx.x >> 6;
    const int lane = threadIdx.x & 63;
    const unsigned c0 = (blockIdx.x * 4u + wid) * 4u;   // 4 chunks per wave
    const int r32  = lane & 31;
    const int koct = (lane >> 5) * 8;

#pragma unroll
    for (int i = 0; i < 4; ++i) {
        const unsigned c = c0 + i;
        const float* src;
        unsigned K16;
        if (c < WCH0) {                       // A region: x (arr0) / h (arr1)
            const unsigned arr = c >> 13, rel = c & 8191u;
            const unsigned M32 = rel >> 5;
            K16 = rel & 31u;
            src = (arr ? h : x) + (size_t)(M32 * 32 + r32) * 512u;
        } else {                              // W region
            const unsigned rel = c - WCH0;
            K16 = rel & 31u;
            const unsigned gn32 = rel >> 5;
            const unsigned g = gn32 >> 4, N32 = gn32 & 15u;
            const unsigned rowLocal = (g % 3u) * 512u + N32 * 32u + r32;
            src = (g < 3 ? wih : whh) + (size_t)rowLocal * 512u;
        }
        const float* p = src + K16 * 16 + koct;
        float4 v0 = *(const float4*)p;
        float4 v1 = *(const float4*)(p + 4);
        f16x8 o;
        o[0] = (_Float16)v0.x; o[1] = (_Float16)v0.y;
        o[2] = (_Float16)v0.z; o[3] = (_Float16)v0.w;
        o[4] = (_Float16)v1.x; o[5] = (_Float16)v1.y;
        o[6] = (_Float16)v1.z; o[7] = (_Float16)v1.w;
        *(f16x8*)(ws + (size_t)c * 512u + lane * 8) = o;
    }
}

// ---------------- main: f16 MFMA GEMM, KT=16, 32KB dbuf, 3 blocks/CU -------
// Slab = 16 chunks x 512 f16 = 16KB: A chunk (arr*2+mtc)*512 [0,2048),
// W chunk 2048 + (g*2+ntc)*512. One barrier per step; prefetch step+1
// issued right after the barrier. Chunk ids are K16-contiguous, so the
// per-step global advance is exactly step*1024 bytes.
__global__ __launch_bounds__(256, 3) void qgru_f16_kt16(
    const _Float16* __restrict__ ws, const float* __restrict__ hid,
    const float* __restrict__ bih, const float* __restrict__ bhh,
    float* __restrict__ out)
{
    __shared__ __align__(16) _Float16 lds[16384];   // 32 KB (2 x 16KB slabs)

    const int t = threadIdx.x, lane = t & 63, wid = t >> 6;
    const int mt = wid >> 1, nt = wid & 1;
    const int m0 = blockIdx.x * BM, n0 = blockIdx.y * BN;

    // per-wave DMA tables: 4 chunks/wave/step
    unsigned goff[4];   // ws byte offset at step 0 (+ lane*16)
    int      ldst[4];   // slab-relative f16 index
    if (wid == 0) {     // A: c = arr*2 + mtc
#pragma unroll
        for (int c = 0; c < 4; ++c) {
            const int arr = c >> 1, mtc = c & 1;
            const unsigned ch = (unsigned)arr * 8192u
                              + (unsigned)((m0 >> 5) + mtc) * 32u;
            goff[c] = ch * 1024u + (unsigned)lane * 16u;
            ldst[c] = c * 512;
        }
    } else {            // W: wave w covers gates 2(w-1), 2(w-1)+1
#pragma unroll
        for (int c = 0; c < 4; ++c) {
            const int g = (wid - 1) * 2 + (c >> 1), ntc = c & 1;
            const unsigned ch = WCH0
                              + (unsigned)((g * 16 + (n0 >> 5) + ntc) * 32);
            goff[c] = ch * 1024u + (unsigned)lane * 16u;
            ldst[c] = 2048 + (g * 2 + ntc) * 512;
        }
    }

    f32x16 acc[6];
#pragma unroll
    for (int g = 0; g < 6; ++g)
#pragma unroll
        for (int i = 0; i < 16; ++i) acc[g][i] = 0.0f;

    const char* wsb = (const char*)ws;
    const int lfo = (lane >> 5) * 256 + (lane & 31) * 8;   // frag offset in chunk

    // pre-issue step 0 into slab 0
#pragma unroll
    for (int c = 0; c < 4; ++c)
        dma16(wsb + goff[c], &lds[ldst[c]]);

    for (int step = 0; step < 32; ++step) {
        __syncthreads();   // DMA for this slab done; prev reads of other slab done

        if (step + 1 < 32) {
            const unsigned kb = (unsigned)(step + 1) * 1024u;
            const int nb = ((step + 1) & 1) * 8192;
#pragma unroll
            for (int c = 0; c < 4; ++c)
                dma16(wsb + goff[c] + kb, &lds[nb + ldst[c]]);
        }

        const int cb = (step & 1) * 8192;
        const f16x8 ax = *(const f16x8*)&lds[cb + mt * 512 + lfo];
        const f16x8 ah = *(const f16x8*)&lds[cb + (2 + mt) * 512 + lfo];
#pragma unroll
        for (int g = 0; g < 6; ++g) {
            const f16x8 b = *(const f16x8*)&lds[cb + 2048 + (g * 2 + nt) * 512 + lfo];
            acc[g] = __builtin_amdgcn_mfma_f32_32x32x16_f16(
                         g < 3 ? ax : ah, b, acc[g], 0, 0, 0);
        }
    }

    // ---- epilogue: quantized GRU gate chain ----
    constexpr float S14 = 16384.0f,     I14 = 1.0f / 16384.0f;
    constexpr float S15 = 32768.0f,     I15 = 1.0f / 32768.0f;
    constexpr float S27 = 134217728.0f, I27 = 1.0f / 134217728.0f;

    const int lh = lane >> 5, l32 = lane & 31;
    const int n = n0 + nt * 32 + l32;
    const float br = bih[n], bi = bih[n + 512], bn = bih[n + 1024];
    const float cr = bhh[n], ci = bhh[n + 512], cn = bhh[n + 1024];

#pragma unroll
    for (int r = 0; r < 16; ++r) {
        const int row = (r & 3) + 8 * (r >> 2) + 4 * lh;
        const int m   = m0 + mt * 32 + row;
        const float hv = hid[(size_t)m * Hsz + n];

        float gir = qround(acc[0][r] + br, S14, I14);
        float gii = qround(acc[1][r] + bi, S14, I14);
        float gin = qround(acc[2][r] + bn, S14, I14);
        float ghr = qround(acc[3][r] + cr, S14, I14);
        float ghi = qround(acc[4][r] + ci, S14, I14);
        float ghn = qround(acc[5][r] + cn, S14, I14);
        float resetg = qsigmoid_dev(gir + ghr);
        float inputg = qsigmoid_dev(gii + ghi);
        float hn  = qround(ghn, S27, I27);
        float rh  = qround(resetg * hn, S15, I15);
        float newg = qtanh_dev(rh + gin);
        float nh  = qround(hv, S15, I15);
        out[(size_t)m * Hsz + n] = newg + inputg * (nh - newg);
    }
}

// ---------------- fallback: bf16x3 (used only if ws too small) -------------
__global__ __launch_bounds__(256, 2) void qgru_mfma_bf16x3(
    const float* __restrict__ x, const float* __restrict__ hid,
    const float* __restrict__ wih, const float* __restrict__ whh,
    const float* __restrict__ bih, const float* __restrict__ bhh,
    float* __restrict__ out)
{
    __shared__ __align__(16) unsigned short lds[16384];

    const int t = threadIdx.x, lane = t & 63, wid = t >> 6;
    const int mt = wid >> 1, nt = wid & 1;
    const int m0 = blockIdx.x * BM, n0 = blockIdx.y * BN;
    const int s_r = t >> 2, s_k = (t & 3) << 2;
    const int s_kh = s_k >> 3, s_j = s_k & 7, s_rt = s_r >> 5, s_r32 = s_r & 31;

    const float* gA[2];
    gA[0] = x   + (size_t)(m0 + s_r) * Ksz + s_k;
    gA[1] = hid + (size_t)(m0 + s_r) * Ksz + s_k;
    const float* gW[6];
#pragma unroll
    for (int g = 0; g < 3; ++g) {
        gW[g]     = wih + (size_t)(g * Hsz + n0 + s_r) * Ksz + s_k;
        gW[g + 3] = whh + (size_t)(g * Hsz + n0 + s_r) * Ksz + s_k;
    }
    const int lh = lane >> 5, l32 = lane & 31;

    f32x16 acc[6];
#pragma unroll
    for (int g = 0; g < 6; ++g)
#pragma unroll
        for (int i = 0; i < 16; ++i) acc[g][i] = 0.0f;

    float4 vA[2], vW[6];
#pragma unroll
    for (int tt = 0; tt < 2; ++tt) vA[tt] = *(const float4*)gA[tt];
#pragma unroll
    for (int g = 0; g < 6; ++g)    vW[g]  = *(const float4*)gW[g];

    for (int k0 = 0; k0 < Ksz; k0 += 16) {
        __syncthreads();
#pragma unroll
        for (int tt = 0; tt < 2; ++tt) {
            unsigned h0, h1, l0, l1;
            split2(vA[tt].x, vA[tt].y, h0, l0);
            split2(vA[tt].z, vA[tt].w, h1, l1);
            unsigned bH = ((((tt*2+0)*2+s_rt)*2+s_kh)*32+s_r32)*8 + s_j;
            unsigned bL = ((((tt*2+1)*2+s_rt)*2+s_kh)*32+s_r32)*8 + s_j;
            *reinterpret_cast<uint2*>(&lds[bH]) = make_uint2(h0, h1);
            *reinterpret_cast<uint2*>(&lds[bL]) = make_uint2(l0, l1);
        }
#pragma unroll
        for (int g = 0; g < 6; ++g) {
            unsigned h0, h1, l0, l1;
            split2(vW[g].x, vW[g].y, h0, l0);
            split2(vW[g].z, vW[g].w, h1, l1);
            unsigned bH = 4096u + ((((g*2+0)*2+s_rt)*2+s_kh)*32+s_r32)*8 + s_j;
            unsigned bL = 4096u + ((((g*2+1)*2+s_rt)*2+s_kh)*32+s_r32)*8 + s_j;
            *reinterpret_cast<uint2*>(&lds[bH]) = make_uint2(h0, h1);
            *reinterpret_cast<uint2*>(&lds[bL]) = make_uint2(l0, l1);
        }
        __syncthreads();
        const int kn = (k0 + 16 < Ksz) ? (k0 + 16) : 0;
#pragma unroll
        for (int tt = 0; tt < 2; ++tt) vA[tt] = *(const float4*)(gA[tt] + kn);
#pragma unroll
        for (int g = 0; g < 6; ++g)    vW[g]  = *(const float4*)(gW[g] + kn);

        const bf16x8 ax_hi = *reinterpret_cast<const bf16x8*>(&lds[((((0)*2+mt)*2+lh)*32+l32)*8]);
        const bf16x8 ax_lo = *reinterpret_cast<const bf16x8*>(&lds[((((1)*2+mt)*2+lh)*32+l32)*8]);
        const bf16x8 ah_hi = *reinterpret_cast<const bf16x8*>(&lds[((((2)*2+mt)*2+lh)*32+l32)*8]);
        const bf16x8 ah_lo = *reinterpret_cast<const bf16x8*>(&lds[((((3)*2+mt)*2+lh)*32+l32)*8]);
#pragma unroll
        for (int g = 0; g < 6; ++g) {
            const bf16x8 b_hi = *reinterpret_cast<const bf16x8*>(&lds[4096u + ((((g*2+0)*2+nt)*2+lh)*32+l32)*8]);
            const bf16x8 b_lo = *reinterpret_cast<const bf16x8*>(&lds[4096u + ((((g*2+1)*2+nt)*2+lh)*32+l32)*8]);
            const bf16x8 a_hi = (g < 3) ? ax_hi : ah_hi;
            const bf16x8 a_lo = (g < 3) ? ax_lo : ah_lo;
            acc[g] = __builtin_amdgcn_mfma_f32_32x32x16_bf16(a_hi, b_hi, acc[g], 0, 0, 0);
            acc[g] = __builtin_amdgcn_mfma_f32_32x32x16_bf16(a_hi, b_lo, acc[g], 0, 0, 0);
            acc[g] = __builtin_amdgcn_mfma_f32_32x32x16_bf16(a_lo, b_hi, acc[g], 0, 0, 0);
        }
    }

    constexpr float S14 = 16384.0f,     I14 = 1.0f / 16384.0f;
    constexpr float S15 = 32768.0f,     I15 = 1.0f / 32768.0f;
    constexpr float S27 = 134217728.0f, I27 = 1.0f / 134217728.0f;
    const int n = n0 + nt * 32 + l32;
    const float br = bih[n], bi = bih[n + 512], bn = bih[n + 1024];
    const float cr = bhh[n], ci = bhh[n + 512], cn = bhh[n + 1024];
#pragma unroll
    for (int r = 0; r < 16; ++r) {
        const int row = (r & 3) + 8 * (r >> 2) + 4 * lh;
        const int m   = m0 + mt * 32 + row;
        const float hv = hid[(size_t)m * Hsz + n];
        float gir = qround(acc[0][r] + br, S14, I14);
        float gii = qround(acc[1][r] + bi, S14, I14);
        float gin = qround(acc[2][r] + bn, S14, I14);
        float ghr = qround(acc[3][r] + cr, S14, I14);
        float ghi = qround(acc[4][r] + ci, S14, I14);
        float ghn = qround(acc[5][r] + cn, S14, I14);
        float resetg = qsigmoid_dev(gir + ghr);
        float inputg = qsigmoid_dev(gii + ghi);
        float hn  = qround(ghn, S27, I27);
        float rh  = qround(resetg * hn, S15, I15);
        float newg = qtanh_dev(rh + gin);
        float nh  = qround(hv, S15, I15);
        out[(size_t)m * Hsz + n] = newg + inputg * (nh - newg);
    }
}

extern "C" void kernel_launch(void* const* d_in, const int* in_sizes, int n_in,
                              void* d_out, int out_size, void* d_ws, size_t ws_size,
                              hipStream_t stream) {
    const float* x   = (const float*)d_in[0];
    const float* hid = (const float*)d_in[1];
    const float* wih = (const float*)d_in[2];
    const float* whh = (const float*)d_in[3];
    const float* bih = (const float*)d_in[4];
    const float* bhh = (const float*)d_in[5];
    float* out = (float*)d_out;
    dim3 grid(Bsz / BM, Hsz / BN);   // x-major: consecutive blocks share W chunks

    if (ws_size >= WS_NEED) {
        cvt_gather_f16<<<NCHUNK / 16, 256, 0, stream>>>(
            x, hid, wih, whh, (_Float16*)d_ws);
        qgru_f16_kt16<<<grid, dim3(256), 0, stream>>>(
            (const _Float16*)d_ws, hid, bih, bhh, out);
    } else {
        qgru_mfma_bf16x3<<<grid, dim3(256), 0, stream>>>(
            x, hid, wih, whh, bih, bhh, out);
    }
}

// Round 7
// 131.045 us; speedup vs baseline: 1.0544x; 1.0544x over previous
//
#include <hip/hip_runtime.h>
#include <math.h>

// QGRUCell — Round 7: LDS-tile-transpose cvt (both global sides coalesced;
// transpose via swizzled LDS) + revert main kernel to R5 KT=32 dbuf (44.6us).
// ws layout unchanged: 512-f16 chunks, A: arr*8192 + M32*32 + K16,
// W: 16384 + (g*16+N32)*32 + K16; chunk pos(row,k)=(k>>3&1)*256+row*8+(k&7).

typedef _Float16 f16x8  __attribute__((ext_vector_type(8)));
typedef _Float16 f16x4  __attribute__((ext_vector_type(4)));
typedef __bf16   bf16x8 __attribute__((ext_vector_type(8)));
typedef float    f32x16 __attribute__((ext_vector_type(16)));

namespace {

constexpr int Bsz = 8192, Ksz = 512, Hsz = 512;
constexpr int BM = 64, BN = 64;

constexpr unsigned WCH0    = 16384u;
constexpr unsigned NCHUNK  = 16384u + 3072u;          // 19456
constexpr unsigned WS_F16  = NCHUNK * 512u;           // 9,961,472 f16
constexpr size_t   WS_NEED = (size_t)WS_F16 * 2;      // 19,922,944 B

__device__ __forceinline__ float qround(float x, float s, float invs) {
    return floorf(x * s + 0.5f) * invs;
}

__device__ __forceinline__ float qsigmoid_dev(float x) {
    float iq = floorf(x * 134217728.0f + 0.5f);
    iq = fminf(fmaxf(iq, -2147483648.0f), 2147483648.0f);
    float e = __expf(-iq * 7.450580596923828125e-9f);
    float s = __builtin_amdgcn_rcpf(1.0f + e);
    float q31 = floorf(s * 2147483648.0f + 0.5f);
    float q15 = floorf(q31 * 1.52587890625e-5f + 0.5f);
    return q15 * 3.0517578125e-5f;
}

__device__ __forceinline__ float qtanh_dev(float x) {
    float iq = floorf(x * 134217728.0f + 0.5f);
    iq = fminf(fmaxf(iq, -2147483648.0f), 2147483648.0f);
    float z = iq * 7.450580596923828125e-9f;
    float e = __expf(2.0f * z);
    float t = 1.0f - 2.0f * __builtin_amdgcn_rcpf(e + 1.0f);
    float q31 = floorf(t * 2147483648.0f + 0.5f);
    float q15 = floorf(q31 * 1.52587890625e-5f + 0.5f);
    return q15 * 3.0517578125e-5f;
}

__device__ __forceinline__ void dma16(const void* g, void* l) {
    __builtin_amdgcn_global_load_lds(
        (const __attribute__((address_space(1))) unsigned int*)g,
        (__attribute__((address_space(3))) unsigned int*)l, 16, 0, 0);
}

__device__ __forceinline__ void split2(float a, float b, unsigned& hi, unsigned& lo) {
    unsigned ua = __float_as_uint(a); ua += 0x7fffu + ((ua >> 16) & 1u);
    unsigned ub = __float_as_uint(b); ub += 0x7fffu + ((ub >> 16) & 1u);
    hi = (ua >> 16) | (ub & 0xffff0000u);
    float ra = a - __uint_as_float(ua & 0xffff0000u);
    float rb = b - __uint_as_float(ub & 0xffff0000u);
    unsigned va = __float_as_uint(ra); va += 0x7fffu + ((va >> 16) & 1u);
    unsigned vb = __float_as_uint(rb); vb += 0x7fffu + ((vb >> 16) & 1u);
    lo = (va >> 16) | (vb & 0xffff0000u);
}

} // namespace

// ---------------- pre-pass: LDS-tile-transpose fp32 -> f16 chunks ----------
// One block per (array, M32) / (g, N32) group: 32 source rows x 512 cols.
// Phase 1: coalesced f32x4 row-major reads -> f16x4 scatter into LDS laid
//   out in chunk order with row swizzle row' = (row + (k>>3)) & 31
//   (store banks = 2*lane mod 32 -> 2-way, free; reads conflict-free).
// Phase 2: each lane reads its 16B frag piece, 1KB contiguous global store
//   per wave-chunk; the group's 32 chunks are consecutive -> 32KB linear.
__global__ __launch_bounds__(256) void cvt_lds_f16(
    const float* __restrict__ x, const float* __restrict__ h,
    const float* __restrict__ wih, const float* __restrict__ whh,
    _Float16* __restrict__ ws)
{
    __shared__ __align__(16) _Float16 lt[16384];   // 32 KB

    const int b   = blockIdx.x;
    const int tid = threadIdx.x;

    const float* src;      // base of the 32-row group (row-major, stride 512)
    unsigned chbase;       // first chunk index of this group
    if (b < 512) {                         // A: x (arr0), h (arr1)
        const int arr = b >> 8, M32 = b & 255;
        src = (arr ? h : x) + (size_t)M32 * 32u * 512u;
        chbase = (unsigned)arr * 8192u + (unsigned)M32 * 32u;
    } else {                               // W: gate g, col-group N32
        const int w = b - 512;             // 0..95
        const int g = w >> 4, N32 = w & 15;
        const int rowLocal = (g % 3) * 512 + N32 * 32;
        src = (g < 3 ? wih : whh) + (size_t)rowLocal * 512u;
        chbase = WCH0 + (unsigned)((g * 16 + N32) * 32);
    }

    // Phase 1: 16 reps x 256 threads covering 32 rows x 128 float4s
#pragma unroll
    for (int rep = 0; rep < 16; ++rep) {
        const int idx = rep * 256 + tid;       // 0..4095
        const int row = idx >> 7;              // 0..31
        const int q   = idx & 127;             // float4 col
        const float4 v = *(const float4*)(src + (size_t)row * 512 + q * 4);
        const int K16  = q >> 2;
        const int kh   = (q >> 1) & 1;
        const int half = (q & 1) * 4;
        const int s    = q >> 1;               // 2*K16 + kh
        const int rsw  = (row + s) & 31;
        f16x4 o;
        o[0] = (_Float16)v.x; o[1] = (_Float16)v.y;
        o[2] = (_Float16)v.z; o[3] = (_Float16)v.w;
        *(f16x4*)&lt[K16 * 512 + kh * 256 + rsw * 8 + half] = o;
    }
    __syncthreads();

    // Phase 2: wave w writes chunks K16 = w*8 .. w*8+7
    const int wid = tid >> 6, lane = tid & 63;
    const int kh  = lane >> 5, row = lane & 31;
#pragma unroll
    for (int cc = 0; cc < 8; ++cc) {
        const int K16 = wid * 8 + cc;
        const int rsw = (row + 2 * K16 + kh) & 31;
        const f16x8 o = *(const f16x8*)&lt[K16 * 512 + kh * 256 + rsw * 8];
        *(f16x8*)(ws + (size_t)(chbase + K16) * 512u + lane * 8) = o;
    }
}

// ---------------- main: R5 kernel verbatim (KT=32, 64KB dbuf) --------------
__global__ __launch_bounds__(256, 2) void qgru_f16_dma2(
    const _Float16* __restrict__ ws, const float* __restrict__ hid,
    const float* __restrict__ bih, const float* __restrict__ bhh,
    float* __restrict__ out)
{
    __shared__ __align__(16) _Float16 lds[32768];   // 64 KB (2 slabs)

    const int t = threadIdx.x, lane = t & 63, wid = t >> 6;
    const int mt = wid >> 1, nt = wid & 1;
    const int m0 = blockIdx.x * BM, n0 = blockIdx.y * BN;

    unsigned goff[8];
    int      ldst[8];
    if (wid == 0) {     // A chunks: c = arr*4 + mtc*2 + ks2
#pragma unroll
        for (int c = 0; c < 8; ++c) {
            int arr = c >> 2, mtc = (c >> 1) & 1, ks2 = c & 1;
            unsigned ch = (unsigned)arr * 8192u
                        + (unsigned)((m0 >> 5) + mtc) * 32u + (unsigned)ks2;
            goff[c] = ch * 1024u + (unsigned)lane * 16u;
            ldst[c] = (arr * 2 + mtc) * 1024 + ks2 * 512;
        }
    } else {            // W chunks: wave w covers gates 2(w-1), 2(w-1)+1
#pragma unroll
        for (int c = 0; c < 8; ++c) {
            int g = (wid - 1) * 2 + (c >> 2), ntc = (c >> 1) & 1, ks2 = c & 1;
            unsigned ch = WCH0
                        + (unsigned)((g * 16 + (n0 >> 5) + ntc) * 32) + (unsigned)ks2;
            goff[c] = ch * 1024u + (unsigned)lane * 16u;
            ldst[c] = 4096 + (g * 2 + ntc) * 1024 + ks2 * 512;
        }
    }

    f32x16 acc[6];
#pragma unroll
    for (int g = 0; g < 6; ++g)
#pragma unroll
        for (int i = 0; i < 16; ++i) acc[g][i] = 0.0f;

    const char* wsb = (const char*)ws;
    const int lr = lane & 31, lk8 = (lane >> 5) * 8;

#pragma unroll
    for (int c = 0; c < 8; ++c)
        dma16(wsb + goff[c], &lds[ldst[c]]);

    for (int step = 0; step < 16; ++step) {
        __syncthreads();

        if (step + 1 < 16) {
            const unsigned kb = (unsigned)(step + 1) * 2048u;
            const int nb = ((step + 1) & 1) * 16384;
#pragma unroll
            for (int c = 0; c < 8; ++c)
                dma16(wsb + goff[c] + kb, &lds[nb + ldst[c]]);
        }

        const int cb = (step & 1) * 16384;
#pragma unroll
        for (int ks2 = 0; ks2 < 2; ++ks2) {
            const int lfo = cb + ks2 * 512 + lk8 * 32 + lr * 8;
            const f16x8 ax = *(const f16x8*)&lds[lfo + (0 + mt) * 1024];
            const f16x8 ah = *(const f16x8*)&lds[lfo + (2 + mt) * 1024];
#pragma unroll
            for (int g = 0; g < 6; ++g) {
                const f16x8 b = *(const f16x8*)&lds[lfo + 4096 + (g * 2 + nt) * 1024];
                acc[g] = __builtin_amdgcn_mfma_f32_32x32x16_f16(
                             g < 3 ? ax : ah, b, acc[g], 0, 0, 0);
            }
        }
    }

    constexpr float S14 = 16384.0f,     I14 = 1.0f / 16384.0f;
    constexpr float S15 = 32768.0f,     I15 = 1.0f / 32768.0f;
    constexpr float S27 = 134217728.0f, I27 = 1.0f / 134217728.0f;

    const int lh = lane >> 5, l32 = lane & 31;
    const int n = n0 + nt * 32 + l32;
    const float br = bih[n], bi = bih[n + 512], bn = bih[n + 1024];
    const float cr = bhh[n], ci = bhh[n + 512], cn = bhh[n + 1024];

#pragma unroll
    for (int r = 0; r < 16; ++r) {
        const int row = (r & 3) + 8 * (r >> 2) + 4 * lh;
        const int m   = m0 + mt * 32 + row;
        const float hv = hid[(size_t)m * Hsz + n];

        float gir = qround(acc[0][r] + br, S14, I14);
        float gii = qround(acc[1][r] + bi, S14, I14);
        float gin = qround(acc[2][r] + bn, S14, I14);
        float ghr = qround(acc[3][r] + cr, S14, I14);
        float ghi = qround(acc[4][r] + ci, S14, I14);
        float ghn = qround(acc[5][r] + cn, S14, I14);
        float resetg = qsigmoid_dev(gir + ghr);
        float inputg = qsigmoid_dev(gii + ghi);
        float hn  = qround(ghn, S27, I27);
        float rh  = qround(resetg * hn, S15, I15);
        float newg = qtanh_dev(rh + gin);
        float nh  = qround(hv, S15, I15);
        out[(size_t)m * Hsz + n] = newg + inputg * (nh - newg);
    }
}

// ---------------- fallback: bf16x3 (used only if ws too small) -------------
__global__ __launch_bounds__(256, 2) void qgru_mfma_bf16x3(
    const float* __restrict__ x, const float* __restrict__ hid,
    const float* __restrict__ wih, const float* __restrict__ whh,
    const float* __restrict__ bih, const float* __restrict__ bhh,
    float* __restrict__ out)
{
    __shared__ __align__(16) unsigned short lds[16384];

    const int t = threadIdx.x, lane = t & 63, wid = t >> 6;
    const int mt = wid >> 1, nt = wid & 1;
    const int m0 = blockIdx.x * BM, n0 = blockIdx.y * BN;
    const int s_r = t >> 2, s_k = (t & 3) << 2;
    const int s_kh = s_k >> 3, s_j = s_k & 7, s_rt = s_r >> 5, s_r32 = s_r & 31;

    const float* gA[2];
    gA[0] = x   + (size_t)(m0 + s_r) * Ksz + s_k;
    gA[1] = hid + (size_t)(m0 + s_r) * Ksz + s_k;
    const float* gW[6];
#pragma unroll
    for (int g = 0; g < 3; ++g) {
        gW[g]     = wih + (size_t)(g * Hsz + n0 + s_r) * Ksz + s_k;
        gW[g + 3] = whh + (size_t)(g * Hsz + n0 + s_r) * Ksz + s_k;
    }
    const int lh = lane >> 5, l32 = lane & 31;

    f32x16 acc[6];
#pragma unroll
    for (int g = 0; g < 6; ++g)
#pragma unroll
        for (int i = 0; i < 16; ++i) acc[g][i] = 0.0f;

    float4 vA[2], vW[6];
#pragma unroll
    for (int tt = 0; tt < 2; ++tt) vA[tt] = *(const float4*)gA[tt];
#pragma unroll
    for (int g = 0; g < 6; ++g)    vW[g]  = *(const float4*)gW[g];

    for (int k0 = 0; k0 < Ksz; k0 += 16) {
        __syncthreads();
#pragma unroll
        for (int tt = 0; tt < 2; ++tt) {
            unsigned h0, h1, l0, l1;
            split2(vA[tt].x, vA[tt].y, h0, l0);
            split2(vA[tt].z, vA[tt].w, h1, l1);
            unsigned bH = ((((tt*2+0)*2+s_rt)*2+s_kh)*32+s_r32)*8 + s_j;
            unsigned bL = ((((tt*2+1)*2+s_rt)*2+s_kh)*32+s_r32)*8 + s_j;
            *reinterpret_cast<uint2*>(&lds[bH]) = make_uint2(h0, h1);
            *reinterpret_cast<uint2*>(&lds[bL]) = make_uint2(l0, l1);
        }
#pragma unroll
        for (int g = 0; g < 6; ++g) {
            unsigned h0, h1, l0, l1;
            split2(vW[g].x, vW[g].y, h0, l0);
            split2(vW[g].z, vW[g].w, h1, l1);
            unsigned bH = 4096u + ((((g*2+0)*2+s_rt)*2+s_kh)*32+s_r32)*8 + s_j;
            unsigned bL = 4096u + ((((g*2+1)*2+s_rt)*2+s_kh)*32+s_r32)*8 + s_j;
            *reinterpret_cast<uint2*>(&lds[bH]) = make_uint2(h0, h1);
            *reinterpret_cast<uint2*>(&lds[bL]) = make_uint2(l0, l1);
        }
        __syncthreads();
        const int kn = (k0 + 16 < Ksz) ? (k0 + 16) : 0;
#pragma unroll
        for (int tt = 0; tt < 2; ++tt) vA[tt] = *(const float4*)(gA[tt] + kn);
#pragma unroll
        for (int g = 0; g < 6; ++g)    vW[g]  = *(const float4*)(gW[g] + kn);

        const bf16x8 ax_hi = *reinterpret_cast<const bf16x8*>(&lds[((((0)*2+mt)*2+lh)*32+l32)*8]);
        const bf16x8 ax_lo = *reinterpret_cast<const bf16x8*>(&lds[((((1)*2+mt)*2+lh)*32+l32)*8]);
        const bf16x8 ah_hi = *reinterpret_cast<const bf16x8*>(&lds[((((2)*2+mt)*2+lh)*32+l32)*8]);
        const bf16x8 ah_lo = *reinterpret_cast<const bf16x8*>(&lds[((((3)*2+mt)*2+lh)*32+l32)*8]);
#pragma unroll
        for (int g = 0; g < 6; ++g) {
            const bf16x8 b_hi = *reinterpret_cast<const bf16x8*>(&lds[4096u + ((((g*2+0)*2+nt)*2+lh)*32+l32)*8]);
            const bf16x8 b_lo = *reinterpret_cast<const bf16x8*>(&lds[4096u + ((((g*2+1)*2+nt)*2+lh)*32+l32)*8]);
            const bf16x8 a_hi = (g < 3) ? ax_hi : ah_hi;
            const bf16x8 a_lo = (g < 3) ? ax_lo : ah_lo;
            acc[g] = __builtin_amdgcn_mfma_f32_32x32x16_bf16(a_hi, b_hi, acc[g], 0, 0, 0);
            acc[g] = __builtin_amdgcn_mfma_f32_32x32x16_bf16(a_hi, b_lo, acc[g], 0, 0, 0);
            acc[g] = __builtin_amdgcn_mfma_f32_32x32x16_bf16(a_lo, b_hi, acc[g], 0, 0, 0);
        }
    }

    constexpr float S14 = 16384.0f,     I14 = 1.0f / 16384.0f;
    constexpr float S15 = 32768.0f,     I15 = 1.0f / 32768.0f;
    constexpr float S27 = 134217728.0f, I27 = 1.0f / 134217728.0f;
    const int n = n0 + nt * 32 + l32;
    const float br = bih[n], bi = bih[n + 512], bn = bih[n + 1024];
    const float cr = bhh[n], ci = bhh[n + 512], cn = bhh[n + 1024];
#pragma unroll
    for (int r = 0; r < 16; ++r) {
        const int row = (r & 3) + 8 * (r >> 2) + 4 * lh;
        const int m   = m0 + mt * 32 + row;
        const float hv = hid[(size_t)m * Hsz + n];
        float gir = qround(acc[0][r] + br, S14, I14);
        float gii = qround(acc[1][r] + bi, S14, I14);
        float gin = qround(acc[2][r] + bn, S14, I14);
        float ghr = qround(acc[3][r] + cr, S14, I14);
        float ghi = qround(acc[4][r] + ci, S14, I14);
        float ghn = qround(acc[5][r] + cn, S14, I14);
        float resetg = qsigmoid_dev(gir + ghr);
        float inputg = qsigmoid_dev(gii + ghi);
        float hn  = qround(ghn, S27, I27);
        float rh  = qround(resetg * hn, S15, I15);
        float newg = qtanh_dev(rh + gin);
        float nh  = qround(hv, S15, I15);
        out[(size_t)m * Hsz + n] = newg + inputg * (nh - newg);
    }
}

extern "C" void kernel_launch(void* const* d_in, const int* in_sizes, int n_in,
                              void* d_out, int out_size, void* d_ws, size_t ws_size,
                              hipStream_t stream) {
    const float* x   = (const float*)d_in[0];
    const float* hid = (const float*)d_in[1];
    const float* wih = (const float*)d_in[2];
    const float* whh = (const float*)d_in[3];
    const float* bih = (const float*)d_in[4];
    const float* bhh = (const float*)d_in[5];
    float* out = (float*)d_out;
    dim3 grid(Bsz / BM, Hsz / BN);   // x-major: consecutive blocks share W chunks

    if (ws_size >= WS_NEED) {
        cvt_lds_f16<<<512 + 96, 256, 0, stream>>>(
            x, hid, wih, whh, (_Float16*)d_ws);
        qgru_f16_dma2<<<grid, dim3(256), 0, stream>>>(
            (const _Float16*)d_ws, hid, bih, bhh, out);
    } else {
        qgru_mfma_bf16x3<<<grid, dim3(256), 0, stream>>>(
            x, hid, wih, whh, bih, bhh, out);
    }
}